// Round 1
// baseline (972.441 us; speedup 1.0000x reference)
//
#include <hip/hip_runtime.h>

// Fixed-point: z <- tanh(W z + x), per-row independent.
// 1 thread = 1 row. z, x, acc in registers (fully unrolled, static indices).
// W accessed with compile-time-constant indices -> wave-uniform -> s_load
// through the scalar cache (16 KB, fully resident after first iteration).
// Per-wave early exit when all 64 rows have ||dz||_inf < EPS_ROW.

#define D 64
#define FP_MAX_ITER 50
#define EPS_ROW 2.5e-4f

__device__ __forceinline__ float fast_tanh(float u) {
    // tanh(u) = 1 - 2/(exp(2u)+1); exp(inf)->inf -> 1, exp(-inf)->0 -> -1
    float e = __expf(2.0f * u);
    return 1.0f - __fdividef(2.0f, e + 1.0f);
}

__global__ __launch_bounds__(256) void tanh_fixed_point_kernel(
    const float* __restrict__ x, const float* __restrict__ W,
    float* __restrict__ out, int B) {
    int r = blockIdx.x * blockDim.x + threadIdx.x;
    if (r >= B) return;

    const float* xr = x + (size_t)r * D;
    float xv[D], z[D], acc[D];

#pragma unroll
    for (int i = 0; i < D / 4; ++i) {
        float4 v = reinterpret_cast<const float4*>(xr)[i];
        xv[4 * i + 0] = v.x; xv[4 * i + 1] = v.y;
        xv[4 * i + 2] = v.z; xv[4 * i + 3] = v.w;
    }
#pragma unroll
    for (int d = 0; d < D; ++d) z[d] = 0.0f;

    for (int it = 0; it < FP_MAX_ITER; ++it) {
#pragma unroll
        for (int d = 0; d < D; ++d) acc[d] = xv[d];
        // acc[d] += sum_j W[d][j] * z[j]; W row-major, d-outer keeps W
        // scalar loads contiguous (s_load_dwordx16 chunks); full unroll
        // makes every W index a literal -> provably uniform.
#pragma unroll
        for (int d = 0; d < D; ++d) {
#pragma unroll
            for (int j = 0; j < D; ++j) {
                acc[d] = fmaf(W[d * D + j], z[j], acc[d]);
            }
        }
        float maxdiff = 0.0f;
#pragma unroll
        for (int d = 0; d < D; ++d) {
            float t = fast_tanh(acc[d]);
            maxdiff = fmaxf(maxdiff, fabsf(t - z[d]));
            z[d] = t;
        }
        if (__all(maxdiff < EPS_ROW)) break;  // wave-uniform branch
    }

    float* outr = out + (size_t)r * D;
#pragma unroll
    for (int i = 0; i < D / 4; ++i) {
        float4 v = make_float4(z[4 * i + 0], z[4 * i + 1],
                               z[4 * i + 2], z[4 * i + 3]);
        reinterpret_cast<float4*>(outr)[i] = v;
    }
}

extern "C" void kernel_launch(void* const* d_in, const int* in_sizes, int n_in,
                              void* d_out, int out_size, void* d_ws, size_t ws_size,
                              hipStream_t stream) {
    const float* x = (const float*)d_in[0];
    const float* W = (const float*)d_in[1];
    float* out = (float*)d_out;
    int B = in_sizes[0] / D;
    int block = 256;
    int grid = (B + block - 1) / block;
    tanh_fixed_point_kernel<<<grid, block, 0, stream>>>(x, W, out, B);
}

// Round 2
// 187.629 us; speedup vs baseline: 5.1828x; 5.1828x over previous
//
#include <hip/hip_runtime.h>

// z <- tanh(W z + x), B=262144 rows, D=64.
// MFMA formulation (swapped operands): C'[d][r] = sum_j W[d][j] z[r][j] + x[r][d]
//   A-fragments = W (bf16, preloaded in registers, iteration-invariant)
//   B-fragments = z^T (bf16, rebuilt in-register each iteration)
//   C = fp32 accumulator, initialized from x each iteration (exact add).
// C' 32x32 layout: lane holds col r=lane&31, rows d=(reg&3)+8*(reg>>2)+4*(lane>>5)
// -> each lane owns one batch row r with d-subset; lo/hi lanes (same r) hold
// complementary d-halves. Next iter's B-fragment (lane needs k=(lane>>5)*8+i)
// is exactly a lo/hi half exchange: v_cvt_pk_bf16_f32 + v_permlane32_swap_b32.
// No LDS anywhere in the loop; ~250-inst body (I-cache resident).

#define D 64
#define ITERS 20

typedef short bf16x8 __attribute__((ext_vector_type(8)));
typedef float f32x16 __attribute__((ext_vector_type(16)));

__device__ __forceinline__ unsigned cvt_pk_bf16(float lo, float hi) {
    unsigned r;
    asm("v_cvt_pk_bf16_f32 %0, %1, %2" : "=v"(r) : "v"(lo), "v"(hi));
    return r;
}

// v_permlane32_swap_b32 a, b:  a' = [a.lo | b.lo], b' = [a.hi | b.hi]
__device__ __forceinline__ void permswap(unsigned &a, unsigned &b) {
    asm("v_permlane32_swap_b32 %0, %1" : "+v"(a), "+v"(b));
}

__device__ __forceinline__ float fast_tanh(float u) {
    // tanh(u) = 1 - 2/(exp(2u)+1); saturates correctly at +/-inf
    float e = __expf(2.0f * u);
    return 1.0f - 2.0f * __frcp_rn(e + 1.0f);
}

__device__ __forceinline__ bf16x8 make_frag(unsigned w0, unsigned w1,
                                            unsigned w2, unsigned w3) {
    union { unsigned u[4]; bf16x8 v; } t;
    t.u[0] = w0; t.u[1] = w1; t.u[2] = w2; t.u[3] = w3;
    return t.v;
}

__global__ __launch_bounds__(256) void tanh_fp_mfma_kernel(
    const float* __restrict__ x, const float* __restrict__ W,
    float* __restrict__ out) {
    const int lane = threadIdx.x & 63;
    const int wave = threadIdx.x >> 6;
    const int col = lane & 31;          // this lane's batch row within the tile
    const int hi  = lane >> 5;
    const size_t r = (size_t)blockIdx.x * 128 + wave * 32 + col;

    // ---- Preload W as A-fragments: wfrag[t][kk] ----
    // A[m][k]: lane holds m = lane&31 (+t*32), k = kk*16 + hi*8 + i, i=0..7
    bf16x8 wfrag[2][4];
#pragma unroll
    for (int t = 0; t < 2; ++t) {
        const int row = t * 32 + col;
#pragma unroll
        for (int kk = 0; kk < 4; ++kk) {
            const int jb = kk * 16 + hi * 8;
            float4 a = *reinterpret_cast<const float4*>(&W[row * D + jb]);
            float4 b = *reinterpret_cast<const float4*>(&W[row * D + jb + 4]);
            wfrag[t][kk] = make_frag(cvt_pk_bf16(a.x, a.y), cvt_pk_bf16(a.z, a.w),
                                     cvt_pk_bf16(b.x, b.y), cvt_pk_bf16(b.z, b.w));
        }
    }

    // ---- Preload x in C'-layout: xf[t][reg] = x[r][t*32 + (reg&3) + 8*(reg>>2) + 4*hi]
    f32x16 xf[2];
#pragma unroll
    for (int t = 0; t < 2; ++t) {
#pragma unroll
        for (int q = 0; q < 4; ++q) {
            float4 v = *reinterpret_cast<const float4*>(
                &x[r * D + t * 32 + q * 8 + hi * 4]);
            xf[t][q * 4 + 0] = v.x; xf[t][q * 4 + 1] = v.y;
            xf[t][q * 4 + 2] = v.z; xf[t][q * 4 + 3] = v.w;
        }
    }

    // ---- Fixed-point loop. acc holds pre-tanh value; first iter: z=0 -> acc=x
    f32x16 acc0 = xf[0], acc1 = xf[1];

    for (int it = 0; it < ITERS; ++it) {
        // z = tanh(acc), in place (fp32)
#pragma unroll
        for (int i = 0; i < 16; ++i) acc0[i] = fast_tanh(acc0[i]);
#pragma unroll
        for (int i = 0; i < 16; ++i) acc1[i] = fast_tanh(acc1[i]);

        if (it == ITERS - 1) break;

        // Pack z to bf16 chunk regs. Chunk m = t*4+q covers j = 8m + 4*hi + {0..3}:
        //   Am = pk(j0,j1), Bm = pk(j2,j3)
        unsigned Am[8], Bm[8];
#pragma unroll
        for (int q = 0; q < 4; ++q) {
            Am[q]     = cvt_pk_bf16(acc0[q * 4 + 0], acc0[q * 4 + 1]);
            Bm[q]     = cvt_pk_bf16(acc0[q * 4 + 2], acc0[q * 4 + 3]);
            Am[4 + q] = cvt_pk_bf16(acc1[q * 4 + 0], acc1[q * 4 + 1]);
            Bm[4 + q] = cvt_pk_bf16(acc1[q * 4 + 2], acc1[q * 4 + 3]);
        }

        // acc = x + W z  (C initialized from x via the first MFMA's C operand)
        f32x16 n0 = xf[0], n1 = xf[1];
#pragma unroll
        for (int kk = 0; kk < 4; ++kk) {
            // B-fragment for k-step kk: lane needs j = kk*16 + hi*8 + {0..7}
            permswap(Am[2 * kk], Am[2 * kk + 1]);  // -> words 0 and 2
            permswap(Bm[2 * kk], Bm[2 * kk + 1]);  // -> words 1 and 3
            bf16x8 zf = make_frag(Am[2 * kk], Bm[2 * kk],
                                  Am[2 * kk + 1], Bm[2 * kk + 1]);
            n0 = __builtin_amdgcn_mfma_f32_32x32x16_bf16(wfrag[0][kk], zf, n0, 0, 0, 0);
            n1 = __builtin_amdgcn_mfma_f32_32x32x16_bf16(wfrag[1][kk], zf, n1, 0, 0, 0);
        }
        acc0 = n0; acc1 = n1;
    }

    // ---- Store z (same strided-float4 pattern as x load; dense across the wave)
#pragma unroll
    for (int t = 0; t < 2; ++t) {
        f32x16 z = t ? acc1 : acc0;
#pragma unroll
        for (int q = 0; q < 4; ++q) {
            float4 v = make_float4(z[q * 4 + 0], z[q * 4 + 1],
                                   z[q * 4 + 2], z[q * 4 + 3]);
            *reinterpret_cast<float4*>(&out[r * D + t * 32 + q * 8 + hi * 4]) = v;
        }
    }
}

extern "C" void kernel_launch(void* const* d_in, const int* in_sizes, int n_in,
                              void* d_out, int out_size, void* d_ws, size_t ws_size,
                              hipStream_t stream) {
    const float* x = (const float*)d_in[0];
    const float* W = (const float*)d_in[1];
    float* out = (float*)d_out;
    const int B = in_sizes[0] / D;          // 262144
    const int grid = B / 128;               // 128 rows per block (4 waves x 32)
    tanh_fp_mfma_kernel<<<grid, 256, 0, stream>>>(x, W, out);
}

// Round 4
// 100.063 us; speedup vs baseline: 9.7183x; 1.8751x over previous
//
#include <hip/hip_runtime.h>

// z <- tanh(W z + x), B=262144 rows, D=64.
// MFMA formulation (swapped operands): C'[d][r] = sum_j W[d][j] z[r][j] + x[r][d]
//   A-fragments = W (bf16, preloaded in registers, iteration-invariant)
//   B-fragments = z^T (bf16, rebuilt in-register each iteration via
//                 v_cvt_pk_bf16_f32 + v_permlane32_swap_b32)
//   C = fp32 accumulator, initialized from x each iteration (exact add).
// tanh = minimal native sequence: mul, v_exp_f32 (=2^x), add, v_rcp_f32, fma.
//   (raw HW approximations, <=1ulp -- fine for 0.02 absmax threshold;
//    __frcp_rn's correctly-rounded div sequence was ~3x the VALU cost)
// No LDS anywhere; loop body small enough to stay I-cache resident.

#define D 64
#define ITERS 20

typedef short bf16x8 __attribute__((ext_vector_type(8)));
typedef float f32x16 __attribute__((ext_vector_type(16)));

__device__ __forceinline__ unsigned cvt_pk_bf16(float lo, float hi) {
    unsigned r;
    asm("v_cvt_pk_bf16_f32 %0, %1, %2" : "=v"(r) : "v"(lo), "v"(hi));
    return r;
}

// v_permlane32_swap_b32 a, b:  a' = [a.lo | b.lo], b' = [a.hi | b.hi]
__device__ __forceinline__ void permswap(unsigned &a, unsigned &b) {
    asm("v_permlane32_swap_b32 %0, %1" : "+v"(a), "+v"(b));
}

__device__ __forceinline__ float fast_tanh(float u) {
    // tanh(u) = 1 - 2/(exp(2u)+1) = 1 - 2/(2^(u*2*log2e)+1)
    // v_exp_f32 computes 2^x. e->inf: rcp->0 -> +1; e->0: rcp(1)=1 -> -1.
    float e = __builtin_amdgcn_exp2f(u * 2.88539008177793f); // v_mul + v_exp_f32
    float r = __builtin_amdgcn_rcpf(e + 1.0f);               // v_add + v_rcp_f32
    return __builtin_fmaf(-2.0f, r, 1.0f);                   // v_fma
}

__device__ __forceinline__ bf16x8 make_frag(unsigned w0, unsigned w1,
                                            unsigned w2, unsigned w3) {
    union { unsigned u[4]; bf16x8 v; } t;
    t.u[0] = w0; t.u[1] = w1; t.u[2] = w2; t.u[3] = w3;
    return t.v;
}

__global__ __launch_bounds__(256) void tanh_fp_mfma_kernel(
    const float* __restrict__ x, const float* __restrict__ W,
    float* __restrict__ out) {
    const int lane = threadIdx.x & 63;
    const int wave = threadIdx.x >> 6;
    const int col = lane & 31;          // this lane's batch row within the tile
    const int hi  = lane >> 5;
    const size_t r = (size_t)blockIdx.x * 128 + wave * 32 + col;

    // ---- Preload W as A-fragments: wfrag[t][kk] ----
    // A[m][k]: lane holds m = lane&31 (+t*32), k = kk*16 + hi*8 + i, i=0..7
    bf16x8 wfrag[2][4];
#pragma unroll
    for (int t = 0; t < 2; ++t) {
        const int row = t * 32 + col;
#pragma unroll
        for (int kk = 0; kk < 4; ++kk) {
            const int jb = kk * 16 + hi * 8;
            float4 a = *reinterpret_cast<const float4*>(&W[row * D + jb]);
            float4 b = *reinterpret_cast<const float4*>(&W[row * D + jb + 4]);
            wfrag[t][kk] = make_frag(cvt_pk_bf16(a.x, a.y), cvt_pk_bf16(a.z, a.w),
                                     cvt_pk_bf16(b.x, b.y), cvt_pk_bf16(b.z, b.w));
        }
    }

    // ---- Preload x in C'-layout: xf[t][reg] = x[r][t*32 + (reg&3) + 8*(reg>>2) + 4*hi]
    f32x16 xf[2];
#pragma unroll
    for (int t = 0; t < 2; ++t) {
#pragma unroll
        for (int q = 0; q < 4; ++q) {
            float4 v = *reinterpret_cast<const float4*>(
                &x[r * D + t * 32 + q * 8 + hi * 4]);
            xf[t][q * 4 + 0] = v.x; xf[t][q * 4 + 1] = v.y;
            xf[t][q * 4 + 2] = v.z; xf[t][q * 4 + 3] = v.w;
        }
    }

    // ---- Fixed-point loop. acc holds pre-tanh value; first iter: z=0 -> acc=x
    f32x16 acc0 = xf[0], acc1 = xf[1];

    for (int it = 0; it < ITERS; ++it) {
        // z = tanh(acc), in place (fp32)
#pragma unroll
        for (int i = 0; i < 16; ++i) acc0[i] = fast_tanh(acc0[i]);
#pragma unroll
        for (int i = 0; i < 16; ++i) acc1[i] = fast_tanh(acc1[i]);

        if (it == ITERS - 1) break;

        // Pack z to bf16 chunk regs. Chunk m = t*4+q covers j = 8m + 4*hi + {0..3}:
        //   Am = pk(j0,j1), Bm = pk(j2,j3)
        unsigned Am[8], Bm[8];
#pragma unroll
        for (int q = 0; q < 4; ++q) {
            Am[q]     = cvt_pk_bf16(acc0[q * 4 + 0], acc0[q * 4 + 1]);
            Bm[q]     = cvt_pk_bf16(acc0[q * 4 + 2], acc0[q * 4 + 3]);
            Am[4 + q] = cvt_pk_bf16(acc1[q * 4 + 0], acc1[q * 4 + 1]);
            Bm[4 + q] = cvt_pk_bf16(acc1[q * 4 + 2], acc1[q * 4 + 3]);
        }

        // acc = x + W z  (C initialized from x via the first MFMA's C operand)
        f32x16 n0 = xf[0], n1 = xf[1];
#pragma unroll
        for (int kk = 0; kk < 4; ++kk) {
            // B-fragment for k-step kk: lane needs j = kk*16 + hi*8 + {0..7}
            permswap(Am[2 * kk], Am[2 * kk + 1]);  // -> words 0 and 2
            permswap(Bm[2 * kk], Bm[2 * kk + 1]);  // -> words 1 and 3
            bf16x8 zf = make_frag(Am[2 * kk], Bm[2 * kk],
                                  Am[2 * kk + 1], Bm[2 * kk + 1]);
            n0 = __builtin_amdgcn_mfma_f32_32x32x16_bf16(wfrag[0][kk], zf, n0, 0, 0, 0);
            n1 = __builtin_amdgcn_mfma_f32_32x32x16_bf16(wfrag[1][kk], zf, n1, 0, 0, 0);
        }
        acc0 = n0; acc1 = n1;
    }

    // ---- Store z (same strided-float4 pattern as x load; dense across the wave)
#pragma unroll
    for (int t = 0; t < 2; ++t) {
        f32x16 z = t ? acc1 : acc0;
#pragma unroll
        for (int q = 0; q < 4; ++q) {
            float4 v = make_float4(z[q * 4 + 0], z[q * 4 + 1],
                                   z[q * 4 + 2], z[q * 4 + 3]);
            *reinterpret_cast<float4*>(&out[r * D + t * 32 + q * 8 + hi * 4]) = v;
        }
    }
}

extern "C" void kernel_launch(void* const* d_in, const int* in_sizes, int n_in,
                              void* d_out, int out_size, void* d_ws, size_t ws_size,
                              hipStream_t stream) {
    const float* x = (const float*)d_in[0];
    const float* W = (const float*)d_in[1];
    float* out = (float*)d_out;
    const int B = in_sizes[0] / D;          // 262144
    const int grid = B / 128;               // 128 rows per block (4 waves x 32)
    tanh_fp_mfma_kernel<<<grid, 256, 0, stream>>>(x, W, out);
}